// Round 9
// baseline (114.877 us; speedup 1.0000x reference)
//
#include <hip/hip_runtime.h>
#include <math.h>
#include <stdint.h>

#define NJ 14
#define NE 42              // floats per item per tensor
#define TPB 64             // ONE wave per block -> wave-synchronous, zero barriers
#define NS 4               // slices per persistent wave (amortize per-slice latency)
#define SLICE_DW (NE * 64)  // 2688 dwords per tensor-slice
#define BUF_DW 2816         // +128 dw pad (tail dma16 writes 64 lanes x 16B)
#define SWEEPS 3           // verified bit-exact vs reference (R6 absmax 0.0)

__device__ __forceinline__ float frcp(float x) { return __builtin_amdgcn_rcpf(x); }
__device__ __forceinline__ float frsq(float x) { return __builtin_amdgcn_rsqf(x); }
__device__ __forceinline__ float fsqr(float x) { return __builtin_amdgcn_sqrtf(x); }

typedef uint32_t u32_as1 __attribute__((address_space(1)));
typedef uint32_t u32_as3 __attribute__((address_space(3)));

__device__ __forceinline__ void dma16(const float* g, const float* l) {
    __builtin_amdgcn_global_load_lds((const u32_as1*)(uintptr_t)g,
                                     (u32_as3*)(uintptr_t)l, 16, 0, 0);
}

// Stage one tensor's slice: 11 x dma16 (tail op clamped; lanes>=32 hit the pad).
__device__ __forceinline__ void stage1(const float* __restrict__ g, int blk,
                                       int lim4, int lane, float* dst) {
#pragma unroll
    for (int k = 0; k < 10; ++k)
        dma16(g + blk + k * 256 + lane * 4, dst + k * 256);
    int a = blk + 2560 + lane * 4;
    a = a > lim4 ? lim4 : a;
    dma16(g + a, dst + 2560);
}

// Branchless cyclic Jacobi rotation on symmetric A, accumulating V.
template <int p, int q, int r>
__device__ __forceinline__ void jrot(float A[3][3], float V[3][3]) {
    float apq = A[p][q];
    float apq_s = apq + copysignf(1e-30f, apq);
    float tau = (A[q][q] - A[p][p]) * 0.5f * frcp(apq_s);
    float t = copysignf(frcp(fabsf(tau) + fsqr(1.0f + tau * tau)), tau);
    float c = frsq(1.0f + t * t);
    float s = t * c;
    float app = A[p][p], aqq = A[q][q];
    A[p][p] = app - t * apq;
    A[q][q] = aqq + t * apq;
    A[p][q] = 0.0f;
    A[q][p] = 0.0f;
    float arp = A[r][p], arq = A[r][q];
    A[r][p] = c * arp - s * arq;
    A[p][r] = A[r][p];
    A[r][q] = s * arp + c * arq;
    A[q][r] = A[r][q];
#pragma unroll
    for (int k = 0; k < 3; ++k) {
        float vkp = V[k][p], vkq = V[k][q];
        V[k][p] = c * vkp - s * vkq;
        V[k][q] = s * vkp + c * vkq;
    }
}

// Persistent-wave pipeline (the ONE untried structural axis after R1-R8
// falsified HBM-trips / spill / occupancy / chain-length / ILP / wg-size):
// each wave owns NS=4 consecutive slices; slice i+1's 22 DMAs are issued
// BEFORE computing slice i; s_waitcnt vmcnt(22) waits only for the current
// slice -> the memory pipe never drains (T3/T4 counted-vmcnt discipline).
// Per-slice compute body is R3/R6's verified all-DMA body.
__global__ __launch_bounds__(TPB) void pampjpe_kernel(
    const float* __restrict__ pred, const float* __restrict__ gt,
    float* __restrict__ out, int n_items) {
    __shared__ float s[4 * BUF_DW];  // {P0,G0,P1,G1} = 45056 B

    const int lane = threadIdx.x;
    const int base_slice = blockIdx.x * NS;
    const int totdw = n_items * NE;
    const int lim4 = totdw - 4;
    const float invJ = 1.0f / (float)NJ;

    // ---- prologue: stage slice 0 into buffer 0 (22 DMAs) ----
    {
        int blk = base_slice * SLICE_DW;
        stage1(pred, blk, lim4, lane, s);
        stage1(gt, blk, lim4, lane, s + BUF_DW);
    }

#pragma unroll
    for (int i = 0; i < NS; ++i) {
        const int slice = base_slice + i;
        const int b = i & 1;

        // ---- prefetch slice i+1 into the other buffer pair ----
        if (i + 1 < NS) {
            // iter i-1's ds_reads of this buffer must retire before DMA lands
            __asm__ __volatile__("s_waitcnt lgkmcnt(0)" ::: "memory");
            int blk = (slice + 1) * SLICE_DW;
            float* pb = s + ((i + 1) & 1) * 2 * BUF_DW;
            stage1(pred, blk, lim4, lane, pb);
            stage1(gt, blk, lim4, lane, pb + BUF_DW);
            // 44 outstanding; wait for the oldest 22 (current slice) only
            __asm__ __volatile__("s_waitcnt vmcnt(22)" ::: "memory");
        } else {
            __asm__ __volatile__("s_waitcnt vmcnt(0)" ::: "memory");
        }
        __builtin_amdgcn_sched_barrier(0);

        const float* sp = s + b * 2 * BUF_DW + lane * NE;
        const float* sg = s + b * 2 * BUF_DW + BUF_DW + lane * NE;

        // ---- pass 1: moments (streamed from LDS, nothing kept) ----
        float Sp0 = 0.f, Sp1 = 0.f, Sp2 = 0.f;
        float Sg0 = 0.f, Sg1 = 0.f, Sg2 = 0.f;
        float pp = 0.f;
        float M[3][3] = {{0.f, 0.f, 0.f}, {0.f, 0.f, 0.f}, {0.f, 0.f, 0.f}};
#pragma unroll
        for (int j = 0; j < NJ; ++j) {
            float px = sp[3 * j + 0], py = sp[3 * j + 1], pz = sp[3 * j + 2];
            float gx = sg[3 * j + 0], gy = sg[3 * j + 1], gz = sg[3 * j + 2];
            Sp0 += px; Sp1 += py; Sp2 += pz;
            Sg0 += gx; Sg1 += gy; Sg2 += gz;
            pp += px * px + py * py + pz * pz;
            M[0][0] += px * gx; M[0][1] += px * gy; M[0][2] += px * gz;
            M[1][0] += py * gx; M[1][1] += py * gy; M[1][2] += py * gz;
            M[2][0] += pz * gx; M[2][1] += pz * gy; M[2][2] += pz * gz;
        }
        // Anti-spill fence (round-2 lesson): pass-1 LDS reads die here; pass 2
        // re-streams from LDS instead of keeping 84 floats live across Jacobi.
        __asm__ __volatile__("" ::: "memory");

        float mp[3] = {Sp0 * invJ, Sp1 * invJ, Sp2 * invJ};
        float mg[3] = {Sg0 * invJ, Sg1 * invJ, Sg2 * invJ};

        float K[3][3];
#pragma unroll
        for (int ii = 0; ii < 3; ++ii)
#pragma unroll
            for (int jj = 0; jj < 3; ++jj)
                K[ii][jj] = M[ii][jj] - (float)NJ * mp[ii] * mg[jj];
        float var1 =
            pp - (float)NJ * (mp[0] * mp[0] + mp[1] * mp[1] + mp[2] * mp[2]);
        var1 = fmaxf(var1, 1e-30f);

        // ---- A = K^T K, Jacobi ----
        float A[3][3];
#pragma unroll
        for (int ii = 0; ii < 3; ++ii)
#pragma unroll
            for (int jj = 0; jj < 3; ++jj)
                A[ii][jj] = K[0][ii] * K[0][jj] + K[1][ii] * K[1][jj] +
                            K[2][ii] * K[2][jj];
        float V[3][3] = {{1.f, 0.f, 0.f}, {0.f, 1.f, 0.f}, {0.f, 0.f, 1.f}};
#pragma unroll
        for (int sweep = 0; sweep < SWEEPS; ++sweep) {
            jrot<0, 1, 2>(A, V);
            jrot<0, 2, 1>(A, V);
            jrot<1, 2, 0>(A, V);
        }
        float lam0 = A[0][0], lam1 = A[1][1], lam2 = A[2][2];

#define SWAPCOL(la, lb, a, bb)                                    \
    {                                                             \
        float _t;                                                 \
        _t = la; la = lb; lb = _t;                                \
        _t = V[0][a]; V[0][a] = V[0][bb]; V[0][bb] = _t;          \
        _t = V[1][a]; V[1][a] = V[1][bb]; V[1][bb] = _t;          \
        _t = V[2][a]; V[2][a] = V[2][bb]; V[2][bb] = _t;          \
    }
        if (lam0 < lam1) SWAPCOL(lam0, lam1, 0, 1)
        if (lam0 < lam2) SWAPCOL(lam0, lam2, 0, 2)
        if (lam1 < lam2) SWAPCOL(lam1, lam2, 1, 2)
#undef SWAPCOL

        float v0[3] = {V[0][0], V[1][0], V[2][0]};
        float v1[3] = {V[0][1], V[1][1], V[2][1]};
        float v2[3] = {V[0][2], V[1][2], V[2][2]};

        // det(V) = +1
        float cxx = v0[1] * v1[2] - v0[2] * v1[1];
        float cxy = v0[2] * v1[0] - v0[0] * v1[2];
        float cxz = v0[0] * v1[1] - v0[1] * v1[0];
        float detv = cxx * v2[0] + cxy * v2[1] + cxz * v2[2];
        if (detv < 0.f) { v2[0] = -v2[0]; v2[1] = -v2[1]; v2[2] = -v2[2]; }

        // U via K*v + Gram-Schmidt; u3 = u1 x u2 -> det(U)=+1
        float w0[3], w1[3];
#pragma unroll
        for (int ii = 0; ii < 3; ++ii) {
            w0[ii] = K[ii][0] * v0[0] + K[ii][1] * v0[1] + K[ii][2] * v0[2];
            w1[ii] = K[ii][0] * v1[0] + K[ii][1] * v1[1] + K[ii][2] * v1[2];
        }
        float inv0 =
            frsq(fmaxf(w0[0] * w0[0] + w0[1] * w0[1] + w0[2] * w0[2], 1e-30f));
        float u1[3] = {w0[0] * inv0, w0[1] * inv0, w0[2] * inv0};
        float d1 = u1[0] * w1[0] + u1[1] * w1[1] + u1[2] * w1[2];
        w1[0] -= d1 * u1[0]; w1[1] -= d1 * u1[1]; w1[2] -= d1 * u1[2];
        float inv1 =
            frsq(fmaxf(w1[0] * w1[0] + w1[1] * w1[1] + w1[2] * w1[2], 1e-30f));
        float u2[3] = {w1[0] * inv1, w1[1] * inv1, w1[2] * inv1};
        float u3[3] = {u1[1] * u2[2] - u1[2] * u2[1],
                       u1[2] * u2[0] - u1[0] * u2[2],
                       u1[0] * u2[1] - u1[1] * u2[0]};

        // R = V U^T; fold scale in
        float R[3][3];
#pragma unroll
        for (int ii = 0; ii < 3; ++ii) {
            R[ii][0] = v0[ii] * u1[0] + v1[ii] * u2[0] + v2[ii] * u3[0];
            R[ii][1] = v0[ii] * u1[1] + v1[ii] * u2[1] + v2[ii] * u3[1];
            R[ii][2] = v0[ii] * u1[2] + v1[ii] * u2[2] + v2[ii] * u3[2];
        }
        float trRK = 0.f;
#pragma unroll
        for (int ii = 0; ii < 3; ++ii)
#pragma unroll
            for (int jj = 0; jj < 3; ++jj)
                trRK += R[ii][jj] * K[jj][ii];
        float scale = trRK * frcp(var1);
        float sR[3][3];
#pragma unroll
        for (int ii = 0; ii < 3; ++ii)
#pragma unroll
            for (int jj = 0; jj < 3; ++jj)
                sR[ii][jj] = scale * R[ii][jj];

        // ---- pass 2: loss (both tensors re-streamed from LDS) ----
        float acc = 0.f;
#pragma unroll
        for (int j = 0; j < NJ; ++j) {
            float x0 = sp[3 * j + 0] - mp[0];
            float x1 = sp[3 * j + 1] - mp[1];
            float x2 = sp[3 * j + 2] - mp[2];
            float y0 = sg[3 * j + 0] - mg[0];
            float y1 = sg[3 * j + 1] - mg[1];
            float y2 = sg[3 * j + 2] - mg[2];
            float e0 = sR[0][0] * x0 + sR[0][1] * x1 + sR[0][2] * x2 - y0;
            float e1 = sR[1][0] * x0 + sR[1][1] * x1 + sR[1][2] * x2 - y1;
            float e2 = sR[2][0] * x0 + sR[2][1] * x1 + sR[2][2] * x2 - y2;
            acc += fsqr(e0 * e0 + e1 * e1 + e2 * e2);
        }
        const int me = slice * 64 + lane;
        if (me < n_items) out[me] = acc * invJ;
    }
}

extern "C" void kernel_launch(void* const* d_in, const int* in_sizes, int n_in,
                              void* d_out, int out_size, void* d_ws, size_t ws_size,
                              hipStream_t stream) {
    const float* pred = (const float*)d_in[0];
    const float* gt = (const float*)d_in[1];
    float* out = (float*)d_out;
    int n_items = in_sizes[0] / NE;                    // 262144
    int n_slices = (n_items + 63) / 64;                // 4096
    int grid = (n_slices + NS - 1) / NS;               // 1024
    pampjpe_kernel<<<grid, TPB, 0, stream>>>(pred, gt, out, n_items);
}